// Round 14
// baseline (20.666 us; speedup 1.0000x reference)
//
#include <hip/hip_runtime.h>
#include <math.h>

#define NCLS 20
#define B_N 128
#define A_N 5
#define H_N 26
#define W_N 26
#define HW_N (H_N * W_N)            // 676
#define M_N 64
#define CH_N (5 + NCLS)             // 25
#define HALF_LOC (HW_N / 2)         // 338 locations per half-plane
#define HALF_T (HALF_LOC / 2)       // 169 active threads (2 locs each)
#define BLK_T 192                   // 3 waves
#define WIN_BLKS B_N                // 128 winner blocks (first in grid)
#define NOOBJ_BLKS (B_N * A_N * 2)  // 1280 half-plane blocks
#define SLOTS_PER_B (A_N * 2)       // 10 per-block slots per batch

typedef _Float16 h2 __attribute__((ext_vector_type(2)));

__device__ __forceinline__ float fastrcp(float x) { return __builtin_amdgcn_rcpf(x); }
__device__ __forceinline__ float sigmoidf_(float x) { return fastrcp(1.0f + __expf(-x)); }
__device__ __forceinline__ h2 h2min(h2 a, h2 b) { return __builtin_elementwise_min(a, b); }
__device__ __forceinline__ h2 h2max(h2 a, h2 b) { return __builtin_elementwise_max(a, b); }
__device__ __forceinline__ h2 h2fma(h2 a, h2 b, h2 c) { return __builtin_elementwise_fma(a, b, c); }
__device__ __forceinline__ unsigned packh2(float lo, float hi) {
    h2 v; v.x = (_Float16)lo; v.y = (_Float16)hi;
    return __builtin_bit_cast(unsigned, v);
}
__device__ __forceinline__ h2 ash2(unsigned u) { return __builtin_bit_cast(h2, u); }
__device__ __forceinline__ unsigned rdl(unsigned v, int m) {
    return (unsigned)__builtin_amdgcn_readlane((int)v, m);
}

// ---------------------------------------------------------------------------
// Main kernel: 128 winner blocks + 1280 noobj half-plane blocks.
// noobj loop: gts live in per-lane REGISTERS (lane m = gt m); v_readlane
// broadcast (3 dwords/gt) + uniform SALU half-duplication + 7 packed-f16
// VALU ops serve BOTH of the thread's locations -> zero LDS in the loop.
// Winner path exact fp32 (unchanged from R9). Two dispatches (fusion is
// unsafe across XCDs - proven R10/R12/R13).
// ---------------------------------------------------------------------------
__global__ __launch_bounds__(BLK_T) void main_kernel(
    const float* __restrict__ outputs, const float* __restrict__ targets,
    const float* __restrict__ anchors,
    float* __restrict__ A_part, float* __restrict__ H_part,
    int* __restrict__ any_part,
    float* __restrict__ Gb, float* __restrict__ Asub, float* __restrict__ Hsub,
    int* __restrict__ nobjArr) {
    int blk = blockIdx.x;
    bool winnerBlk = (blk < WIN_BLKS);
    int tid = threadIdx.x;
    if (winnerBlk && tid >= M_N) return;    // winner blocks: wave 0 only
    int lane = tid & 63;

    int b, a, half;
    if (winnerBlk) { b = blk; a = 0; half = 0; }
    else {
        int nb = blk - WIN_BLKS;
        int plane = nb >> 1; half = nb & 1;
        b = plane / A_N; a = plane % A_N;
    }

    __shared__ float4 sg4[M_N];     // winner blocks only
    __shared__ int skey[M_N];
    __shared__ float rA[3], rH[3];
    __shared__ int rAny[3];

    // ---- every thread loads its own gt row (lane = row); waves independent --
    const float* trow = targets + ((size_t)b * M_N + lane) * 5;
    float tc = trow[0], tx = trow[1], ty = trow[2], tw = trow[3], th = trow[4];

    // ---- early-issue O-plane loads (noobj), overlap with gt build ----
    bool act = false;
    float2 O0, O1, O2, O3, O4;
    int hw0 = 0;
    if (!winnerBlk) {
        act = (tid < HALF_T);
        if (act) {
            hw0 = half * HALF_LOC + tid * 2;
            const float* op = outputs +
                ((size_t)b * (A_N * CH_N) + (size_t)a * CH_N) * HW_N + hw0;
            O0 = *(const float2*)(op + 0 * HW_N);
            O1 = *(const float2*)(op + 1 * HW_N);
            O2 = *(const float2*)(op + 2 * HW_N);
            O3 = *(const float2*)(op + 3 * HW_N);
            O4 = *(const float2*)(op + 4 * HW_N);
        }
    }

    bool valid = (tc + tx + ty + tw + th) > 0.0f;   // valid rows are a prefix
    unsigned long long mask = __ballot(valid);
    int nobj = __popcll(mask);                      // wave-uniform
    float gx = tx * (float)W_N, gy = ty * (float)H_N;
    float gw = tw * (float)W_N, gh = th * (float)H_N;
    float x0 = gx - gw * 0.5f, y0 = gy - gh * 0.5f;
    float x1 = gx + gw * 0.5f, y1 = gy + gh * 0.5f;
    // zero rows (invalid) -> zero boxes: inter clamps to 0, s=0 < pa (harmless)
    unsigned boxA = packh2(x0, y0);                 // lane m holds gt m packed
    unsigned boxB = packh2(x1, y1);
    unsigned ngaU = packh2(-(gw * gh), -(gw * gh));

    if (winnerBlk) {
        // ================= winner path (wave 0, lane == m) =================
        sg4[lane] = make_float4(x0, y0, x1, y1);
        __syncthreads();                            // single wave: cheap
        float G = 0.0f, c2A = 0.0f, c2H = 0.0f;
        float4 g4 = sg4[lane];
        float ga = gw * gh;
        int cell = (int)floorf(gy) * W_N + (int)floorf(gx);
        cell = min(max(cell, 0), HW_N - 1);
        int ccx = cell % W_N, ccy = cell / W_N;
        float best = -1.0f;
        int ai = 0; float aw = 1.0f, ah = 1.0f;
        #pragma unroll
        for (int aa = 0; aa < A_N; ++aa) {
            float anw = anchors[2 * aa], anh = anchors[2 * aa + 1];
            float atlx = (float)ccx + 0.5f - anw * 0.5f;
            float atly = (float)ccy + 0.5f - anh * 0.5f;
            float ix = fminf(atlx + anw, g4.z) - fmaxf(atlx, g4.x);
            float iy = fminf(atly + anh, g4.w) - fmaxf(atly, g4.y);
            float inter = fmaxf(ix, 0.0f) * fmaxf(iy, 0.0f);
            float ov = inter * fastrcp(anw * anh + ga - inter);
            if (ov > best) { best = ov; ai = aa; aw = anw; ah = anh; }
        }
        skey[lane] = valid ? (cell * A_N + ai) : (-1 - lane);
        __syncthreads();
        // winner = last valid m holding its key (lax.scan overwrite)
        bool winner = valid;
        if (valid) {
            int mykey = skey[lane];
            for (int mm = lane + 1; mm < M_N; ++mm)
                if (skey[mm] == mykey) winner = false;
        }

        if (winner) {
            size_t obase = ((size_t)b * (A_N * CH_N) + (size_t)ai * CH_N) * HW_N + cell;
            float o0 = outputs[obase + 0 * HW_N];
            float o1 = outputs[obase + 1 * HW_N];
            float o2 = outputs[obase + 2 * HW_N];
            float o3 = outputs[obase + 3 * HW_N];
            float o4 = outputs[obase + 4 * HW_N];
            float sx = sigmoidf_(o0), sy = sigmoidf_(o1);
            float ew = __expf(o2), eh = __expf(o3);
            float conf = sigmoidf_(o4);
            float px = sx + (float)ccx, py = sy + (float)ccy;
            float pw = ew * aw, ph = eh * ah;
            float tlx = px - pw * 0.5f, tly = py - ph * 0.5f;
            float brx = px + pw * 0.5f, bry = py + ph * 0.5f;
            float pa = pw * ph;

            float mi = 0.0f, maxdW = -1e30f;
            for (int mm = 0; mm < nobj; ++mm) {
                float4 g = sg4[mm];
                float gaM = (g.z - g.x) * (g.w - g.y);
                float ix = fminf(brx, g.z) - fmaxf(tlx, g.x);
                float iy = fminf(bry, g.w) - fmaxf(tly, g.y);
                float in = fmaxf(ix, 0.0f) * fmaxf(iy, 0.0f);
                mi = fmaxf(mi, in * fastrcp(pa + gaM - in));
                maxdW = fmaxf(maxdW, fmaf(3.0f, in, -(pa + gaM)));
            }

            float dcf = conf - mi;
            G = dcf * dcf;
            float bs = 2.0f - (pw / (float)W_N) * (ph / (float)H_N);
            float e0 = sx - (gx - (float)ccx);
            float e1 = sy - (gy - (float)ccy);
            float e2 = ew - gw / aw;
            float e3 = eh - gh / ah;
            G += bs * (e0 * e0 + e1 * e1 + e2 * e2 + e3 * e3);

            int cls = (int)tc;
            float mx = -1e30f, tv = 0.0f, logits[NCLS];
            #pragma unroll
            for (int c = 0; c < NCLS; ++c) {
                logits[c] = outputs[obase + (size_t)(5 + c) * HW_N];
                mx = fmaxf(mx, logits[c]);
            }
            float se = 0.0f;
            #pragma unroll
            for (int c = 0; c < NCLS; ++c) {
                se += __expf(logits[c] - mx);
                if (c == cls) tv = logits[c];
            }
            G += (mx + __logf(se)) - tv;

            c2A = conf * conf;                       // noobj-sum corrections
            c2H = (maxdW >= 0.0f) ? c2A : 0.0f;
        }
        #pragma unroll
        for (int off = 32; off > 0; off >>= 1) {
            G   += __shfl_down(G, off);
            c2A += __shfl_down(c2A, off);
            c2H += __shfl_down(c2H, off);
        }
        if (lane == 0) {
            Gb[b] = G; Asub[b] = c2A; Hsub[b] = c2H; nobjArr[b] = nobj;
        }
    } else {
        // ==== noobj path: packed-f16, 2 locs/thread, readlane broadcast ====
        float pa0 = 1e30f, pa1 = 1e30f;
        h2 tlxH, tlyH, brxH, bryH;
        {
            float tlx0 = 0, tly0 = 0, brx0 = 0, bry0 = 0;
            float tlx1 = 0, tly1 = 0, brx1 = 0, bry1 = 0;
            if (act) {
                int wy = hw0 / W_N;
                int wx = hw0 - wy * W_N;    // hw0 even, W even -> same row
                float aw = anchors[2 * a], ah = anchors[2 * a + 1];
                float sx0 = sigmoidf_(O0.x), sx1 = sigmoidf_(O0.y);
                float sy0 = sigmoidf_(O1.x), sy1 = sigmoidf_(O1.y);
                float pw0 = __expf(O2.x) * aw, pw1 = __expf(O2.y) * aw;
                float ph0 = __expf(O3.x) * ah, ph1 = __expf(O3.y) * ah;
                float px0 = sx0 + (float)wx, px1 = sx1 + (float)(wx + 1);
                float py0 = sy0 + (float)wy, py1 = sy1 + (float)wy;
                tlx0 = px0 - pw0 * 0.5f; tly0 = py0 - ph0 * 0.5f;
                brx0 = px0 + pw0 * 0.5f; bry0 = py0 + ph0 * 0.5f;
                tlx1 = px1 - pw1 * 0.5f; tly1 = py1 - ph1 * 0.5f;
                brx1 = px1 + pw1 * 0.5f; bry1 = py1 + ph1 * 0.5f;
                pa0 = pw0 * ph0; pa1 = pw1 * ph1;
            }
            tlxH = ash2(packh2(tlx0, tlx1));
            tlyH = ash2(packh2(tly0, tly1));
            brxH = ash2(packh2(brx0, brx1));
            bryH = ash2(packh2(bry0, bry1));
        }

        h2 h3; h3.x = (_Float16)3.0f; h3.y = (_Float16)3.0f;
        h2 hzero; hzero.x = (_Float16)0.0f; hzero.y = (_Float16)0.0f;
        h2 msA; msA.x = (_Float16)(-60000.0f); msA.y = (_Float16)(-60000.0f);
        h2 msB = msA;

        // s = 3*inter - ga (packed over 2 locations); iou>=0.5 <=> s >= pa.
        // Broadcast gt mm from lane mm: 3 readlanes; half-duplication is
        // uniform (SALU); 7 packed-f16 VALU ops per gt serve both locations.
        for (int m = 0; m < nobj; m += 4) {
            #pragma unroll
            for (int k = 0; k < 4; ++k) {
                int mm = m + k;                      // always < 64
                unsigned dA = rdl(boxA, mm);
                unsigned dB = rdl(boxB, mm);
                unsigned dN = rdl(ngaU, mm);
                h2 gx2 = ash2((dA & 0xffffu) * 0x10001u);   // dup lo (SALU)
                h2 gy2 = ash2((dA >> 16) * 0x10001u);       // dup hi (SALU)
                h2 gz2 = ash2((dB & 0xffffu) * 0x10001u);
                h2 gw2 = ash2((dB >> 16) * 0x10001u);
                h2 nga = ash2(dN);
                h2 ix = h2min(brxH, gz2) - h2max(tlxH, gx2);
                h2 iy = h2min(bryH, gw2) - h2max(tlyH, gy2);
                h2 in = h2max(ix, hzero) * h2max(iy, hzero);
                if (k & 1) msB = h2max(msB, h2fma(h3, in, nga));
                else       msA = h2max(msA, h2fma(h3, in, nga));
            }
        }
        h2 ms = h2max(msA, msB);
        float ms0 = (float)ms.x, ms1 = (float)ms.y;

        float locA = 0.0f, locH = 0.0f;
        bool any = false;
        if (act) {
            float conf0 = sigmoidf_(O4.x), conf1 = sigmoidf_(O4.y);
            float c20 = conf0 * conf0, c21 = conf1 * conf1;
            locA = c20 + c21;
            locH = (ms0 >= pa0 ? c20 : 0.0f) + (ms1 >= pa1 ? c21 : 0.0f);
            any = (ms0 > pa0) || (ms1 > pa1);
        }

        int wany = __any(any) ? 1 : 0;
        #pragma unroll
        for (int off = 32; off > 0; off >>= 1) {
            locA += __shfl_down(locA, off);
            locH += __shfl_down(locH, off);
        }
        int w = tid >> 6;
        if (lane == 0) { rA[w] = locA; rH[w] = locH; rAny[w] = wany; }
        __syncthreads();
        if (tid == 0) {
            int nb = blk - WIN_BLKS;
            A_part[nb] = rA[0] + rA[1] + rA[2];
            H_part[nb] = rH[0] + rH[1] + rH[2];
            any_part[nb] = rAny[0] | rAny[1] | rAny[2];
        }
    }
}

// ---------------------------------------------------------------------------
// Finish: 128 threads, one per batch; fixed-order deterministic reduction.
// Separate dispatch -> kernel-boundary fences make all writes visible.
// ---------------------------------------------------------------------------
__global__ __launch_bounds__(128) void finish_kernel(
    const float* __restrict__ A_part, const float* __restrict__ H_part,
    const int* __restrict__ any_part,
    const float* __restrict__ Gb, const float* __restrict__ Asub,
    const float* __restrict__ Hsub, const int* __restrict__ nobjArr,
    float* __restrict__ out) {
    int t = threadIdx.x;  // == b
    float A = -Asub[t], Hs = -Hsub[t];
    int any = 0;
    #pragma unroll
    for (int j = 0; j < SLOTS_PER_B; ++j) {
        A += A_part[t * SLOTS_PER_B + j];
        Hs += H_part[t * SLOTS_PER_B + j];
        any |= any_part[t * SLOTS_PER_B + j];
    }
    float noobj = (nobjArr[t] > 0) ? (A - (any ? Hs : 0.0f)) : 0.0f;
    float v = Gb[t] + noobj;
    #pragma unroll
    for (int off = 32; off > 0; off >>= 1) v += __shfl_down(v, off);
    __shared__ float r[2];
    if ((t & 63) == 0) r[t >> 6] = v;
    __syncthreads();
    if (t == 0) out[0] = (r[0] + r[1]) / (float)B_N;
}

extern "C" void kernel_launch(void* const* d_in, const int* in_sizes, int n_in,
                              void* d_out, int out_size, void* d_ws, size_t ws_size,
                              hipStream_t stream) {
    const float* outputs = (const float*)d_in[0];
    const float* targets = (const float*)d_in[1];
    const float* anchors = (const float*)d_in[2];
    float* out = (float*)d_out;

    char* ws = (char*)d_ws;
    size_t off = 0;
    float* A_part = (float*)(ws + off); off += 4 * (size_t)NOOBJ_BLKS;
    float* H_part = (float*)(ws + off); off += 4 * (size_t)NOOBJ_BLKS;
    int* any_part = (int*)(ws + off);   off += 4 * (size_t)NOOBJ_BLKS;
    float* Gb = (float*)(ws + off);     off += 4 * B_N;
    float* Asub = (float*)(ws + off);   off += 4 * B_N;
    float* Hsub = (float*)(ws + off);   off += 4 * B_N;
    int* nobjArr = (int*)(ws + off);    off += 4 * B_N;
    // every slot above is unconditionally written each call -> no memset needed

    main_kernel<<<WIN_BLKS + NOOBJ_BLKS, BLK_T, 0, stream>>>(
        outputs, targets, anchors,
        A_part, H_part, any_part, Gb, Asub, Hsub, nobjArr);

    finish_kernel<<<1, 128, 0, stream>>>(A_part, H_part, any_part,
                                         Gb, Asub, Hsub, nobjArr, out);
}

// Round 15
// 20.180 us; speedup vs baseline: 1.0241x; 1.0241x over previous
//
#include <hip/hip_runtime.h>
#include <math.h>

#define NCLS 20
#define B_N 128
#define A_N 5
#define H_N 26
#define W_N 26
#define HW_N (H_N * W_N)            // 676
#define M_N 64
#define CH_N (5 + NCLS)             // 25
#define HALF_LOC (HW_N / 2)         // 338 locations per half-plane
#define HALF_T (HALF_LOC / 2)       // 169 active noobj threads (2 locs each)
#define BLK_T 256                   // 4 waves: 0-2 noobj, 3 winner (128 blocks)
#define NOOBJ_BLKS (B_N * A_N * 2)  // 1280 half-plane blocks == whole grid
#define SLOTS_PER_B (A_N * 2)       // 10 per-block slots per batch

typedef _Float16 h2 __attribute__((ext_vector_type(2)));

__device__ __forceinline__ float fastrcp(float x) { return __builtin_amdgcn_rcpf(x); }
__device__ __forceinline__ float sigmoidf_(float x) { return fastrcp(1.0f + __expf(-x)); }
__device__ __forceinline__ h2 h2min(h2 a, h2 b) { return __builtin_elementwise_min(a, b); }
__device__ __forceinline__ h2 h2max(h2 a, h2 b) { return __builtin_elementwise_max(a, b); }
__device__ __forceinline__ h2 h2fma(h2 a, h2 b, h2 c) { return __builtin_elementwise_fma(a, b, c); }
__device__ __forceinline__ unsigned packh2(float lo, float hi) {
    h2 v; v.x = (_Float16)lo; v.y = (_Float16)hi;
    return __builtin_bit_cast(unsigned, v);
}
__device__ __forceinline__ h2 ash2(unsigned u) { return __builtin_bit_cast(h2, u); }

// ---------------------------------------------------------------------------
// Main kernel: 1280 blocks x 256 threads. Waves 0-2: R9's packed-f16 noobj
// path for one half-plane (2 locs/thread, LDS gt tiles). Wave 3: winner
// (positive-sample) path, active only in the 128 (a==0,half==0) blocks --
// its scattered HBM latency hides under the block's own noobj work.
// Two dispatches total (single-dispatch fusion is HW-unsafe: R10/R12/R13).
// ---------------------------------------------------------------------------
__global__ __launch_bounds__(BLK_T) void main_kernel(
    const float* __restrict__ outputs, const float* __restrict__ targets,
    const float* __restrict__ anchors,
    float* __restrict__ A_part, float* __restrict__ H_part,
    int* __restrict__ any_part,
    float* __restrict__ Gb, float* __restrict__ Asub, float* __restrict__ Hsub,
    int* __restrict__ nobjArr) {
    int nb = blockIdx.x;
    int plane = nb >> 1, half = nb & 1;
    int b = plane / A_N, a = plane % A_N;
    int tid = threadIdx.x;
    int lane = tid & 63, w = tid >> 6;
    bool winWave = (w == 3) && (a == 0) && (half == 0);  // wave-uniform

    __shared__ uint4 sgq[M_N];       // duplicated-half2 gt boxes (noobj)
    __shared__ unsigned snga[M_N];   // duplicated -ga as half2 bits (noobj)
    __shared__ float4 sg4[M_N];      // fp32 gt boxes (winner wave)
    __shared__ int skey[M_N];        // winner-resolution keys
    __shared__ int snobj;
    __shared__ float rA[3], rH[3];
    __shared__ int rAny[3];

    // ---- early-issue O-plane loads (noobj threads), overlap staging ----
    bool act = (w < 3) && (tid < HALF_T);
    float2 O0, O1, O2, O3, O4;
    int hw0 = 0;
    if (act) {
        hw0 = half * HALF_LOC + tid * 2;
        const float* op = outputs +
            ((size_t)b * (A_N * CH_N) + (size_t)a * CH_N) * HW_N + hw0;
        O0 = *(const float2*)(op + 0 * HW_N);
        O1 = *(const float2*)(op + 1 * HW_N);
        O2 = *(const float2*)(op + 2 * HW_N);
        O3 = *(const float2*)(op + 3 * HW_N);
        O4 = *(const float2*)(op + 4 * HW_N);
    }

    // ---- staging: wave 0 builds f16 LDS boxes; winner wave keeps fp32 ----
    float tc = 0, gx = 0, gy = 0, gw = 0, gh = 0;
    bool valid = false;
    if (w == 0 || winWave) {         // wave-uniform entry per wave
        const float* trow = targets + ((size_t)b * M_N + lane) * 5;
        tc = trow[0];
        float tx = trow[1], ty = trow[2], tw = trow[3], th = trow[4];
        valid = (tc + tx + ty + tw + th) > 0.0f;    // valid rows are a prefix
        unsigned long long mask = __ballot(valid);
        gx = tx * (float)W_N; gy = ty * (float)H_N;
        gw = tw * (float)W_N; gh = th * (float)H_N;
        float x0 = gx - gw * 0.5f, y0 = gy - gh * 0.5f;
        float x1 = gx + gw * 0.5f, y1 = gy + gh * 0.5f;
        if (w == 0) {
            if (lane == 0) snobj = __popcll(mask);
            // invalid rows = zero boxes -> inter clamps to 0, -ga=0 (harmless)
            uint4 q;
            q.x = packh2(x0, x0); q.y = packh2(y0, y0);
            q.z = packh2(x1, x1); q.w = packh2(y1, y1);
            sgq[lane] = q;
            snga[lane] = packh2(-(gw * gh), -(gw * gh));
        } else {
            sg4[lane] = make_float4(x0, y0, x1, y1);
        }
    }
    __syncthreads();
    int nobj = snobj;

    if (winWave) {
        // ================= winner path (wave 3, lane == m) =================
        float G = 0.0f, c2A = 0.0f, c2H = 0.0f;
        float ga = gw * gh;
        float4 g4 = sg4[lane];
        int cell = (int)floorf(gy) * W_N + (int)floorf(gx);
        cell = min(max(cell, 0), HW_N - 1);
        int ccx = cell % W_N, ccy = cell / W_N;
        float best = -1.0f;
        int ai = 0; float aw = 1.0f, ah = 1.0f;
        #pragma unroll
        for (int aa = 0; aa < A_N; ++aa) {
            float anw = anchors[2 * aa], anh = anchors[2 * aa + 1];
            float atlx = (float)ccx + 0.5f - anw * 0.5f;
            float atly = (float)ccy + 0.5f - anh * 0.5f;
            float ix = fminf(atlx + anw, g4.z) - fmaxf(atlx, g4.x);
            float iy = fminf(atly + anh, g4.w) - fmaxf(atly, g4.y);
            float inter = fmaxf(ix, 0.0f) * fmaxf(iy, 0.0f);
            float ov = inter * fastrcp(anw * anh + ga - inter);
            if (ov > best) { best = ov; ai = aa; aw = anw; ah = anh; }
        }
        skey[lane] = valid ? (cell * A_N + ai) : (-1 - lane);
        __threadfence_block();       // wave-internal LDS write->read ordering

        // winner = last valid m holding its key (lax.scan overwrite)
        bool winner = valid;
        if (valid) {
            int mykey = skey[lane];
            for (int mm = lane + 1; mm < M_N; ++mm)
                if (skey[mm] == mykey) winner = false;
        }

        if (winner) {
            size_t obase = ((size_t)b * (A_N * CH_N) + (size_t)ai * CH_N) * HW_N + cell;
            float o0 = outputs[obase + 0 * HW_N];
            float o1 = outputs[obase + 1 * HW_N];
            float o2 = outputs[obase + 2 * HW_N];
            float o3 = outputs[obase + 3 * HW_N];
            float o4 = outputs[obase + 4 * HW_N];
            float sx = sigmoidf_(o0), sy = sigmoidf_(o1);
            float ew = __expf(o2), eh = __expf(o3);
            float conf = sigmoidf_(o4);
            float px = sx + (float)ccx, py = sy + (float)ccy;
            float pw = ew * aw, ph = eh * ah;
            float tlx = px - pw * 0.5f, tly = py - ph * 0.5f;
            float brx = px + pw * 0.5f, bry = py + ph * 0.5f;
            float pa = pw * ph;

            float mi = 0.0f, maxdW = -1e30f;
            for (int mm = 0; mm < nobj; ++mm) {
                float4 g = sg4[mm];
                float gaM = (g.z - g.x) * (g.w - g.y);
                float ix = fminf(brx, g.z) - fmaxf(tlx, g.x);
                float iy = fminf(bry, g.w) - fmaxf(tly, g.y);
                float in = fmaxf(ix, 0.0f) * fmaxf(iy, 0.0f);
                mi = fmaxf(mi, in * fastrcp(pa + gaM - in));
                maxdW = fmaxf(maxdW, fmaf(3.0f, in, -(pa + gaM)));
            }

            float dcf = conf - mi;
            G = dcf * dcf;
            float bs = 2.0f - (pw / (float)W_N) * (ph / (float)H_N);
            float e0 = sx - (gx - (float)ccx);
            float e1 = sy - (gy - (float)ccy);
            float e2 = ew - gw / aw;
            float e3 = eh - gh / ah;
            G += bs * (e0 * e0 + e1 * e1 + e2 * e2 + e3 * e3);

            int cls = (int)tc;
            float mx = -1e30f, tv = 0.0f, logits[NCLS];
            #pragma unroll
            for (int c = 0; c < NCLS; ++c) {
                logits[c] = outputs[obase + (size_t)(5 + c) * HW_N];
                mx = fmaxf(mx, logits[c]);
            }
            float se = 0.0f;
            #pragma unroll
            for (int c = 0; c < NCLS; ++c) {
                se += __expf(logits[c] - mx);
                if (c == cls) tv = logits[c];
            }
            G += (mx + __logf(se)) - tv;

            c2A = conf * conf;                       // noobj-sum corrections
            c2H = (maxdW >= 0.0f) ? c2A : 0.0f;      // same ">=0.5" algebra
        }
        #pragma unroll
        for (int off = 32; off > 0; off >>= 1) {
            G   += __shfl_down(G, off);
            c2A += __shfl_down(c2A, off);
            c2H += __shfl_down(c2H, off);
        }
        if (lane == 0) {
            Gb[b] = G; Asub[b] = c2A; Hsub[b] = c2H; nobjArr[b] = nobj;
        }
    } else if (w < 3) {
        // ========= noobj path (R9): packed-f16, 2 locations/thread =========
        float pa0 = 1e30f, pa1 = 1e30f;
        h2 tlxH, tlyH, brxH, bryH;
        {
            float tlx0 = 0, tly0 = 0, brx0 = 0, bry0 = 0;
            float tlx1 = 0, tly1 = 0, brx1 = 0, bry1 = 0;
            if (act) {
                int wy = hw0 / W_N;
                int wx = hw0 - wy * W_N;    // hw0 even, W even -> same row
                float aw = anchors[2 * a], ah = anchors[2 * a + 1];
                float sx0 = sigmoidf_(O0.x), sx1 = sigmoidf_(O0.y);
                float sy0 = sigmoidf_(O1.x), sy1 = sigmoidf_(O1.y);
                float pw0 = __expf(O2.x) * aw, pw1 = __expf(O2.y) * aw;
                float ph0 = __expf(O3.x) * ah, ph1 = __expf(O3.y) * ah;
                float px0 = sx0 + (float)wx, px1 = sx1 + (float)(wx + 1);
                float py0 = sy0 + (float)wy, py1 = sy1 + (float)wy;
                tlx0 = px0 - pw0 * 0.5f; tly0 = py0 - ph0 * 0.5f;
                brx0 = px0 + pw0 * 0.5f; bry0 = py0 + ph0 * 0.5f;
                tlx1 = px1 - pw1 * 0.5f; tly1 = py1 - ph1 * 0.5f;
                brx1 = px1 + pw1 * 0.5f; bry1 = py1 + ph1 * 0.5f;
                pa0 = pw0 * ph0; pa1 = pw1 * ph1;
            }
            tlxH = ash2(packh2(tlx0, tlx1));
            tlyH = ash2(packh2(tly0, tly1));
            brxH = ash2(packh2(brx0, brx1));
            bryH = ash2(packh2(bry0, bry1));
        }

        h2 h3; h3.x = (_Float16)3.0f; h3.y = (_Float16)3.0f;
        h2 hzero; hzero.x = (_Float16)0.0f; hzero.y = (_Float16)0.0f;
        h2 msA; msA.x = (_Float16)(-60000.0f); msA.y = (_Float16)(-60000.0f);
        h2 msB = msA;

        // s = 3*inter - ga (packed over 2 locations); iou>=0.5 <=> s >= pa
        #define IOU_STEP(Q, NGA, ACC)                                          \
        {                                                                      \
            h2 gx2 = ash2((Q).x), gy2 = ash2((Q).y);                           \
            h2 gz2 = ash2((Q).z), gw2 = ash2((Q).w);                           \
            h2 ix = h2min(brxH, gz2) - h2max(tlxH, gx2);                       \
            h2 iy = h2min(bryH, gw2) - h2max(tlyH, gy2);                       \
            h2 in = h2max(ix, hzero) * h2max(iy, hzero);                       \
            ACC = h2max(ACC, h2fma(h3, in, NGA));                              \
        }

        for (int m = 0; m < nobj; m += 4) {
            uint4 q0 = sgq[m + 0], q1 = sgq[m + 1];
            uint4 q2 = sgq[m + 2], q3 = sgq[m + 3];
            h2 n0 = ash2(snga[m + 0]), n1 = ash2(snga[m + 1]);
            h2 n2 = ash2(snga[m + 2]), n3 = ash2(snga[m + 3]);
            IOU_STEP(q0, n0, msA);
            IOU_STEP(q1, n1, msB);
            IOU_STEP(q2, n2, msA);
            IOU_STEP(q3, n3, msB);
        }
        h2 ms = h2max(msA, msB);
        float ms0 = (float)ms.x, ms1 = (float)ms.y;

        float locA = 0.0f, locH = 0.0f;
        bool any = false;
        if (act) {
            float conf0 = sigmoidf_(O4.x), conf1 = sigmoidf_(O4.y);
            float c20 = conf0 * conf0, c21 = conf1 * conf1;
            locA = c20 + c21;
            locH = (ms0 >= pa0 ? c20 : 0.0f) + (ms1 >= pa1 ? c21 : 0.0f);
            any = (ms0 > pa0) || (ms1 > pa1);
        }

        int wany = __any(any) ? 1 : 0;
        #pragma unroll
        for (int off = 32; off > 0; off >>= 1) {
            locA += __shfl_down(locA, off);
            locH += __shfl_down(locH, off);
        }
        if (lane == 0) { rA[w] = locA; rH[w] = locH; rAny[w] = wany; }
    }

    __syncthreads();
    if (tid == 0) {
        A_part[nb] = rA[0] + rA[1] + rA[2];
        H_part[nb] = rH[0] + rH[1] + rH[2];
        any_part[nb] = rAny[0] | rAny[1] | rAny[2];
    }
}

// ---------------------------------------------------------------------------
// Finish: 128 threads, one per batch; fixed-order deterministic reduction.
// Separate dispatch -> kernel-boundary fences make all writes visible.
// ---------------------------------------------------------------------------
__global__ __launch_bounds__(128) void finish_kernel(
    const float* __restrict__ A_part, const float* __restrict__ H_part,
    const int* __restrict__ any_part,
    const float* __restrict__ Gb, const float* __restrict__ Asub,
    const float* __restrict__ Hsub, const int* __restrict__ nobjArr,
    float* __restrict__ out) {
    int t = threadIdx.x;  // == b
    float A = -Asub[t], Hs = -Hsub[t];
    int any = 0;
    #pragma unroll
    for (int j = 0; j < SLOTS_PER_B; ++j) {
        A += A_part[t * SLOTS_PER_B + j];
        Hs += H_part[t * SLOTS_PER_B + j];
        any |= any_part[t * SLOTS_PER_B + j];
    }
    float noobj = (nobjArr[t] > 0) ? (A - (any ? Hs : 0.0f)) : 0.0f;
    float v = Gb[t] + noobj;
    #pragma unroll
    for (int off = 32; off > 0; off >>= 1) v += __shfl_down(v, off);
    __shared__ float r[2];
    if ((t & 63) == 0) r[t >> 6] = v;
    __syncthreads();
    if (t == 0) out[0] = (r[0] + r[1]) / (float)B_N;
}

extern "C" void kernel_launch(void* const* d_in, const int* in_sizes, int n_in,
                              void* d_out, int out_size, void* d_ws, size_t ws_size,
                              hipStream_t stream) {
    const float* outputs = (const float*)d_in[0];
    const float* targets = (const float*)d_in[1];
    const float* anchors = (const float*)d_in[2];
    float* out = (float*)d_out;

    char* ws = (char*)d_ws;
    size_t off = 0;
    float* A_part = (float*)(ws + off); off += 4 * (size_t)NOOBJ_BLKS;
    float* H_part = (float*)(ws + off); off += 4 * (size_t)NOOBJ_BLKS;
    int* any_part = (int*)(ws + off);   off += 4 * (size_t)NOOBJ_BLKS;
    float* Gb = (float*)(ws + off);     off += 4 * B_N;
    float* Asub = (float*)(ws + off);   off += 4 * B_N;
    float* Hsub = (float*)(ws + off);   off += 4 * B_N;
    int* nobjArr = (int*)(ws + off);    off += 4 * B_N;
    // every slot above is unconditionally written each call -> no memset needed

    main_kernel<<<NOOBJ_BLKS, BLK_T, 0, stream>>>(
        outputs, targets, anchors,
        A_part, H_part, any_part, Gb, Asub, Hsub, nobjArr);

    finish_kernel<<<1, 128, 0, stream>>>(A_part, H_part, any_part,
                                         Gb, Asub, Hsub, nobjArr, out);
}

// Round 17
// 18.371 us; speedup vs baseline: 1.1249x; 1.0985x over previous
//
#include <hip/hip_runtime.h>
#include <math.h>

#define NCLS 20
#define B_N 128
#define A_N 5
#define H_N 26
#define W_N 26
#define HW_N (H_N * W_N)            // 676
#define M_N 64
#define CH_N (5 + NCLS)             // 25
#define HALF_LOC (HW_N / 2)         // 338 locations per half-plane
#define HALF_T (HALF_LOC / 2)       // 169 active threads (2 locs each)
#define BLK_T 192                   // 3 waves
#define WIN_BLKS B_N                // 128 winner blocks (first in grid)
#define NOOBJ_BLKS (B_N * A_N * 2)  // 1280 half-plane blocks
#define SLOTS_PER_B (A_N * 2)       // 10 per-block slots per batch

typedef _Float16 h2 __attribute__((ext_vector_type(2)));

__device__ __forceinline__ float fastrcp(float x) { return __builtin_amdgcn_rcpf(x); }
__device__ __forceinline__ float sigmoidf_(float x) { return fastrcp(1.0f + __expf(-x)); }
__device__ __forceinline__ h2 h2min(h2 a, h2 b) { return __builtin_elementwise_min(a, b); }
__device__ __forceinline__ h2 h2max(h2 a, h2 b) { return __builtin_elementwise_max(a, b); }
__device__ __forceinline__ h2 h2fma(h2 a, h2 b, h2 c) { return __builtin_elementwise_fma(a, b, c); }
__device__ __forceinline__ unsigned packh2(float lo, float hi) {
    h2 v; v.x = (_Float16)lo; v.y = (_Float16)hi;
    return __builtin_bit_cast(unsigned, v);
}
__device__ __forceinline__ h2 ash2(unsigned u) { return __builtin_bit_cast(h2, u); }

// ---------------------------------------------------------------------------
// Main kernel: 128 winner blocks + 1280 noobj half-plane blocks.
// noobj loop: packed-f16 sign test (2 locations per v_pk op), branch-free,
// 4-wide manual unroll, dual max accumulators. Winner path exact fp32.
// Two dispatches (single-dispatch fusion is HW/harness-unsafe: R10/12/13/16).
// ---------------------------------------------------------------------------
__global__ __launch_bounds__(BLK_T) void main_kernel(
    const float* __restrict__ outputs, const float* __restrict__ targets,
    const float* __restrict__ anchors,
    float* __restrict__ A_part, float* __restrict__ H_part,
    int* __restrict__ any_part,
    float* __restrict__ Gb, float* __restrict__ Asub, float* __restrict__ Hsub,
    int* __restrict__ nobjArr) {
    int blk = blockIdx.x;
    bool winnerBlk = (blk < WIN_BLKS);
    int tid = threadIdx.x;
    int lane = tid & 63;

    int b, a, half;
    if (winnerBlk) { b = blk; a = 0; half = 0; }
    else {
        int nb = blk - WIN_BLKS;
        int plane = nb >> 1; half = nb & 1;
        b = plane / A_N; a = plane % A_N;
    }

    __shared__ float4 sg4[M_N];      // fp32 boxes (winner blocks only)
    __shared__ uint4 sgq[M_N];       // 4x duplicated-half2 fields (noobj)
    __shared__ unsigned snga[M_N];   // duplicated -ga as half2 bits (noobj)
    __shared__ int skey[M_N];
    __shared__ int snobj;
    __shared__ float rA[3], rH[3];
    __shared__ int rAny[3];

    // ---- early-issue O-plane loads (noobj), overlap with gt staging ----
    bool act = false;
    float2 O0, O1, O2, O3, O4;
    int hw0 = 0;
    if (!winnerBlk) {
        act = (tid < HALF_T);
        if (act) {
            hw0 = half * HALF_LOC + tid * 2;
            const float* op = outputs +
                ((size_t)b * (A_N * CH_N) + (size_t)a * CH_N) * HW_N + hw0;
            O0 = *(const float2*)(op + 0 * HW_N);
            O1 = *(const float2*)(op + 1 * HW_N);
            O2 = *(const float2*)(op + 2 * HW_N);
            O3 = *(const float2*)(op + 3 * HW_N);
            O4 = *(const float2*)(op + 4 * HW_N);
        }
    }

    // ---- staging: wave 0 builds gt boxes in LDS ----
    float tc = 0, gx = 0, gy = 0, gw = 0, gh = 0;
    bool valid = false;
    if (tid < M_N) {
        const float* trow = targets + ((size_t)b * M_N + tid) * 5;
        tc = trow[0];
        float tx = trow[1], ty = trow[2], tw = trow[3], th = trow[4];
        valid = (tc + tx + ty + tw + th) > 0.0f;    // valid rows are a prefix
        unsigned long long mask = __ballot(valid);
        if (tid == 0) snobj = __popcll(mask);
        gx = tx * (float)W_N; gy = ty * (float)H_N;
        gw = tw * (float)W_N; gh = th * (float)H_N;
        float x0 = gx - gw * 0.5f, y0 = gy - gh * 0.5f;
        float x1 = gx + gw * 0.5f, y1 = gy + gh * 0.5f;
        if (winnerBlk) {
            sg4[tid] = make_float4(x0, y0, x1, y1);
        } else {
            // invalid rows are zero boxes -> inter clamps to 0, -ga=0 (harmless)
            uint4 q;
            q.x = packh2(x0, x0); q.y = packh2(y0, y0);
            q.z = packh2(x1, x1); q.w = packh2(y1, y1);
            sgq[tid] = q;
            snga[tid] = packh2(-(gw * gh), -(gw * gh));
        }
    }
    __syncthreads();
    int nobj = snobj;

    if (winnerBlk) {
        if (tid >= M_N) return;                     // waves 1,2 done
        // ================= winner path (wave 0, lane == m) =================
        float G = 0.0f, c2A = 0.0f, c2H = 0.0f;
        float4 g4 = sg4[lane];
        float ga = gw * gh;
        int cell = (int)floorf(gy) * W_N + (int)floorf(gx);
        cell = min(max(cell, 0), HW_N - 1);
        int ccx = cell % W_N, ccy = cell / W_N;
        float best = -1.0f;
        int ai = 0; float aw = 1.0f, ah = 1.0f;
        #pragma unroll
        for (int aa = 0; aa < A_N; ++aa) {
            float anw = anchors[2 * aa], anh = anchors[2 * aa + 1];
            float atlx = (float)ccx + 0.5f - anw * 0.5f;
            float atly = (float)ccy + 0.5f - anh * 0.5f;
            float ix = fminf(atlx + anw, g4.z) - fmaxf(atlx, g4.x);
            float iy = fminf(atly + anh, g4.w) - fmaxf(atly, g4.y);
            float inter = fmaxf(ix, 0.0f) * fmaxf(iy, 0.0f);
            float ov = inter * fastrcp(anw * anh + ga - inter);
            if (ov > best) { best = ov; ai = aa; aw = anw; ah = anh; }
        }
        skey[lane] = valid ? (cell * A_N + ai) : (-1 - lane);
        __syncthreads();
        // winner = last valid m holding its key (lax.scan overwrite)
        bool winner = valid;
        if (valid) {
            int mykey = skey[lane];
            for (int mm = lane + 1; mm < M_N; ++mm)
                if (skey[mm] == mykey) winner = false;
        }

        if (winner) {
            size_t obase = ((size_t)b * (A_N * CH_N) + (size_t)ai * CH_N) * HW_N + cell;
            float o0 = outputs[obase + 0 * HW_N];
            float o1 = outputs[obase + 1 * HW_N];
            float o2 = outputs[obase + 2 * HW_N];
            float o3 = outputs[obase + 3 * HW_N];
            float o4 = outputs[obase + 4 * HW_N];
            float sx = sigmoidf_(o0), sy = sigmoidf_(o1);
            float ew = __expf(o2), eh = __expf(o3);
            float conf = sigmoidf_(o4);
            float px = sx + (float)ccx, py = sy + (float)ccy;
            float pw = ew * aw, ph = eh * ah;
            float tlx = px - pw * 0.5f, tly = py - ph * 0.5f;
            float brx = px + pw * 0.5f, bry = py + ph * 0.5f;
            float pa = pw * ph;

            float mi = 0.0f, maxdW = -1e30f;
            for (int mm = 0; mm < nobj; ++mm) {
                float4 g = sg4[mm];
                float gaM = (g.z - g.x) * (g.w - g.y);
                float ix = fminf(brx, g.z) - fmaxf(tlx, g.x);
                float iy = fminf(bry, g.w) - fmaxf(tly, g.y);
                float in = fmaxf(ix, 0.0f) * fmaxf(iy, 0.0f);
                mi = fmaxf(mi, in * fastrcp(pa + gaM - in));
                maxdW = fmaxf(maxdW, fmaf(3.0f, in, -(pa + gaM)));
            }

            float dcf = conf - mi;
            G = dcf * dcf;
            float bs = 2.0f - (pw / (float)W_N) * (ph / (float)H_N);
            float e0 = sx - (gx - (float)ccx);
            float e1 = sy - (gy - (float)ccy);
            float e2 = ew - gw / aw;
            float e3 = eh - gh / ah;
            G += bs * (e0 * e0 + e1 * e1 + e2 * e2 + e3 * e3);

            int cls = (int)tc;
            float mx = -1e30f, tv = 0.0f, logits[NCLS];
            #pragma unroll
            for (int c = 0; c < NCLS; ++c) {
                logits[c] = outputs[obase + (size_t)(5 + c) * HW_N];
                mx = fmaxf(mx, logits[c]);
            }
            float se = 0.0f;
            #pragma unroll
            for (int c = 0; c < NCLS; ++c) {
                se += __expf(logits[c] - mx);
                if (c == cls) tv = logits[c];
            }
            G += (mx + __logf(se)) - tv;

            c2A = conf * conf;                       // noobj-sum corrections
            c2H = (maxdW >= 0.0f) ? c2A : 0.0f;
        }
        #pragma unroll
        for (int off = 32; off > 0; off >>= 1) {
            G   += __shfl_down(G, off);
            c2A += __shfl_down(c2A, off);
            c2H += __shfl_down(c2H, off);
        }
        if (lane == 0) {
            Gb[b] = G; Asub[b] = c2A; Hsub[b] = c2H; nobjArr[b] = nobj;
        }
    } else {
        // ========= noobj path: packed-f16, 2 locations/thread =========
        float pa0 = 1e30f, pa1 = 1e30f;
        h2 tlxH, tlyH, brxH, bryH;
        {
            float tlx0 = 0, tly0 = 0, brx0 = 0, bry0 = 0;
            float tlx1 = 0, tly1 = 0, brx1 = 0, bry1 = 0;
            if (act) {
                int wy = hw0 / W_N;
                int wx = hw0 - wy * W_N;    // hw0 even, W even -> same row
                float aw = anchors[2 * a], ah = anchors[2 * a + 1];
                float sx0 = sigmoidf_(O0.x), sx1 = sigmoidf_(O0.y);
                float sy0 = sigmoidf_(O1.x), sy1 = sigmoidf_(O1.y);
                float pw0 = __expf(O2.x) * aw, pw1 = __expf(O2.y) * aw;
                float ph0 = __expf(O3.x) * ah, ph1 = __expf(O3.y) * ah;
                float px0 = sx0 + (float)wx, px1 = sx1 + (float)(wx + 1);
                float py0 = sy0 + (float)wy, py1 = sy1 + (float)wy;
                tlx0 = px0 - pw0 * 0.5f; tly0 = py0 - ph0 * 0.5f;
                brx0 = px0 + pw0 * 0.5f; bry0 = py0 + ph0 * 0.5f;
                tlx1 = px1 - pw1 * 0.5f; tly1 = py1 - ph1 * 0.5f;
                brx1 = px1 + pw1 * 0.5f; bry1 = py1 + ph1 * 0.5f;
                pa0 = pw0 * ph0; pa1 = pw1 * ph1;
            }
            tlxH = ash2(packh2(tlx0, tlx1));
            tlyH = ash2(packh2(tly0, tly1));
            brxH = ash2(packh2(brx0, brx1));
            bryH = ash2(packh2(bry0, bry1));
        }

        h2 h3; h3.x = (_Float16)3.0f; h3.y = (_Float16)3.0f;
        h2 hzero; hzero.x = (_Float16)0.0f; hzero.y = (_Float16)0.0f;
        h2 msA; msA.x = (_Float16)(-60000.0f); msA.y = (_Float16)(-60000.0f);
        h2 msB = msA;

        // s = 3*inter - ga (packed over 2 locations); iou>=0.5 <=> s >= pa
        #define IOU_STEP(Q, NGA, ACC)                                          \
        {                                                                      \
            h2 gx2 = ash2((Q).x), gy2 = ash2((Q).y);                           \
            h2 gz2 = ash2((Q).z), gw2 = ash2((Q).w);                           \
            h2 ix = h2min(brxH, gz2) - h2max(tlxH, gx2);                       \
            h2 iy = h2min(bryH, gw2) - h2max(tlyH, gy2);                       \
            h2 in = h2max(ix, hzero) * h2max(iy, hzero);                       \
            ACC = h2max(ACC, h2fma(h3, in, NGA));                              \
        }

        for (int m = 0; m < nobj; m += 4) {
            uint4 q0 = sgq[m + 0], q1 = sgq[m + 1];
            uint4 q2 = sgq[m + 2], q3 = sgq[m + 3];
            h2 n0 = ash2(snga[m + 0]), n1 = ash2(snga[m + 1]);
            h2 n2 = ash2(snga[m + 2]), n3 = ash2(snga[m + 3]);
            IOU_STEP(q0, n0, msA);
            IOU_STEP(q1, n1, msB);
            IOU_STEP(q2, n2, msA);
            IOU_STEP(q3, n3, msB);
        }
        h2 ms = h2max(msA, msB);
        float ms0 = (float)ms.x, ms1 = (float)ms.y;

        float locA = 0.0f, locH = 0.0f;
        bool any = false;
        if (act) {
            float conf0 = sigmoidf_(O4.x), conf1 = sigmoidf_(O4.y);
            float c20 = conf0 * conf0, c21 = conf1 * conf1;
            locA = c20 + c21;
            locH = (ms0 >= pa0 ? c20 : 0.0f) + (ms1 >= pa1 ? c21 : 0.0f);
            any = (ms0 > pa0) || (ms1 > pa1);
        }

        int wany = __any(any) ? 1 : 0;
        #pragma unroll
        for (int off = 32; off > 0; off >>= 1) {
            locA += __shfl_down(locA, off);
            locH += __shfl_down(locH, off);
        }
        int w = tid >> 6;
        if (lane == 0) { rA[w] = locA; rH[w] = locH; rAny[w] = wany; }
        __syncthreads();
        if (tid == 0) {
            int nb = blk - WIN_BLKS;
            A_part[nb] = rA[0] + rA[1] + rA[2];
            H_part[nb] = rH[0] + rH[1] + rH[2];
            any_part[nb] = rAny[0] | rAny[1] | rAny[2];
        }
    }
}

// ---------------------------------------------------------------------------
// Finish: 128 threads, one per batch; fixed-order deterministic reduction.
// Separate dispatch -> kernel-boundary fences make all writes visible.
// ---------------------------------------------------------------------------
__global__ __launch_bounds__(128) void finish_kernel(
    const float* __restrict__ A_part, const float* __restrict__ H_part,
    const int* __restrict__ any_part,
    const float* __restrict__ Gb, const float* __restrict__ Asub,
    const float* __restrict__ Hsub, const int* __restrict__ nobjArr,
    float* __restrict__ out) {
    int t = threadIdx.x;  // == b
    float A = -Asub[t], Hs = -Hsub[t];
    int any = 0;
    #pragma unroll
    for (int j = 0; j < SLOTS_PER_B; ++j) {
        A += A_part[t * SLOTS_PER_B + j];
        Hs += H_part[t * SLOTS_PER_B + j];
        any |= any_part[t * SLOTS_PER_B + j];
    }
    float noobj = (nobjArr[t] > 0) ? (A - (any ? Hs : 0.0f)) : 0.0f;
    float v = Gb[t] + noobj;
    #pragma unroll
    for (int off = 32; off > 0; off >>= 1) v += __shfl_down(v, off);
    __shared__ float r[2];
    if ((t & 63) == 0) r[t >> 6] = v;
    __syncthreads();
    if (t == 0) out[0] = (r[0] + r[1]) / (float)B_N;
}

extern "C" void kernel_launch(void* const* d_in, const int* in_sizes, int n_in,
                              void* d_out, int out_size, void* d_ws, size_t ws_size,
                              hipStream_t stream) {
    const float* outputs = (const float*)d_in[0];
    const float* targets = (const float*)d_in[1];
    const float* anchors = (const float*)d_in[2];
    float* out = (float*)d_out;

    char* ws = (char*)d_ws;
    size_t off = 0;
    float* A_part = (float*)(ws + off); off += 4 * (size_t)NOOBJ_BLKS;
    float* H_part = (float*)(ws + off); off += 4 * (size_t)NOOBJ_BLKS;
    int* any_part = (int*)(ws + off);   off += 4 * (size_t)NOOBJ_BLKS;
    float* Gb = (float*)(ws + off);     off += 4 * B_N;
    float* Asub = (float*)(ws + off);   off += 4 * B_N;
    float* Hsub = (float*)(ws + off);   off += 4 * B_N;
    int* nobjArr = (int*)(ws + off);    off += 4 * B_N;
    // every slot above is unconditionally written each call -> no memset needed

    main_kernel<<<WIN_BLKS + NOOBJ_BLKS, BLK_T, 0, stream>>>(
        outputs, targets, anchors,
        A_part, H_part, any_part, Gb, Asub, Hsub, nobjArr);

    finish_kernel<<<1, 128, 0, stream>>>(A_part, H_part, any_part,
                                         Gb, Asub, Hsub, nobjArr, out);
}